// Round 8
// baseline (166.695 us; speedup 1.0000x reference)
//
#include <hip/hip_runtime.h>

// MGN_NET: 3x NNConv(mean) + ReLU, then pairwise-L1 CBT [35x35]. All fp32.
// R7 -> R8: 5 dispatches -> 3 (gap ~4-5 us each, fitted across R0-R7).
//   x1_k   (145 blk): edge lists + deg -> ws; x1 slices; zero agg3+counters
//   x2_k   (560 blk = 35n x 16og): x2[n, 16-o] end-to-end (unchanged core)
//   p3c_k  (280 blk = 35n x 8iq): layer-3 partials -> agg3 atomics; the
//          LAST block per n (relaxed agent fetch_add on cnt3[n], old==7)
//          computes x3[n]; the LAST node-closer (done==34) runs the CBT.
//          No spinning anywhere: pure forward-progress handoff.
// Coherence notes: agg3/x3/cnt3/done cross-block traffic goes through
// agent-scope (sc1/LLC) atomics and relaxed atomic ld/st; vmcnt is drained
// by __syncthreads before every counter bump, so LLC state is complete when
// the closer observes the count. Everything else is plain cached (kernel
// boundaries provide ordering for x1/x2).

#define NN 35
#define NE 1190
#define MAXE 80

// float offsets into ws
#define OFF_CNT  0       // 35
#define OFF_EL   64      // ints, 35*80 = 2800 -> ends 2864
#define OFF_X1   2944    // 8960 -> 11904
#define OFF_X2   11904   // 8960 -> 20864
#define OFF_X3   20864   // 2240 -> 23104
#define OFF_AGG3 23168   // 2240 -> 25408
#define OFF_CNT3 25408   // u32[35]
#define OFF_DONE 25443   // u32[1]

__device__ __forceinline__ float ld_c(const float* p) {
    return __hip_atomic_load(p, __ATOMIC_RELAXED, __HIP_MEMORY_SCOPE_AGENT);
}
__device__ __forceinline__ void st_c(float* p, float v) {
    __hip_atomic_store(p, v, __ATOMIC_RELAXED, __HIP_MEMORY_SCOPE_AGENT);
}

// ---------------- K1: edge lists + x1 slices + zero agg3/counters ----------
__global__ __launch_bounds__(512) void x1_k(
    float* __restrict__ ws, const float* __restrict__ x,
    const float* __restrict__ ea, const int* __restrict__ ei,
    const float* __restrict__ w1, const float* __restrict__ b1w,
    const float* __restrict__ lin1, const float* __restrict__ b1) {
    __shared__ int elistS[MAXE];
    __shared__ int ecntS;
    __shared__ float partS[8 * 64];
    const int tid = threadIdx.x, bid = blockIdx.x;
    if (bid >= 140) {
        // zero agg3 (2240) + cnt3 (35) + done (1) + pad
        const int idx = (bid - 140) * 512 + tid;
        if (idx < 2304) ws[OFF_AGG3 + idx] = 0.f;
        return;
    }
    const int n = bid >> 2, och = bid & 3;
    if (tid == 0) ecntS = 0;
    __syncthreads();
    for (int e = tid; e < NE; e += 512) {
        if (ei[NE + e] == n) {
            const int p = atomicAdd(&ecntS, 1);
            if (p < MAXE) elistS[p] = e;
        }
    }
    __syncthreads();
    const int deg = ecntS;
    const int dl = deg < MAXE ? deg : MAXE;
    const int ol = tid & 63, ech = tid >> 6;
    const int o = och * 64 + ol;
    const float2* wr = (const float2*)(w1 + o * 6);
    const float2 wv0 = wr[0], wv1 = wr[1], wv2 = wr[2];
    const float bb = b1w[o];
    float a = 0.f;
    for (int k = ech; k < dl; k += 8) {
        const int e = elistS[k];
        const float2* eap = (const float2*)(ea + e * 6);
        const float2 a0 = eap[0], a1 = eap[1], a2 = eap[2];
        float d = bb;
        d = fmaf(a0.x, wv0.x, d); d = fmaf(a0.y, wv0.y, d);
        d = fmaf(a1.x, wv1.x, d); d = fmaf(a1.y, wv1.y, d);
        d = fmaf(a2.x, wv2.x, d); d = fmaf(a2.y, wv2.y, d);
        a = fmaf(x[ei[e]], fmaxf(d, 0.f), a);
    }
    partS[ech * 64 + ol] = a;
    __syncthreads();
    if (ech == 0) {
        float s = a;
#pragma unroll
        for (int p = 1; p < 8; p++) s += partS[p * 64 + ol];
        const float c = fmaxf((float)deg, 1.f);
        ws[OFF_X1 + n * 256 + o] = fmaxf(s / c + x[n] * lin1[o] + b1[o], 0.f);
    }
    if (och == 0) {
        if (tid < dl) ((int*)(ws + OFF_EL))[n * MAXE + tid] = elistS[tid];
        if (tid == 0) ws[OFF_CNT + n] = (float)deg;
    }
}

// ---------------- K2: dst-centric layer 2 -> x2[n, 16-o slice] -------------
__global__ __launch_bounds__(512) void x2_k(
    float* __restrict__ ws, const float* __restrict__ ea,
    const int* __restrict__ ei, const float* __restrict__ w2,
    const float* __restrict__ b2w, const float* __restrict__ lin2,
    const float* __restrict__ b2) {
    __shared__ float smem[11264];          // 45 KiB -> 3 blocks/CU
    float* xsS = smem;                     // 80*128 = 10240
    float* x1S = smem + 10240;             // 256
    float* easS = smem + 10496;            // 480
    int* srcS = (int*)(smem + 10976);      // 80
    int* elS = (int*)(smem + 11056);       // 80
    float* partA = smem;                   // alias xsS (used after compute)
    float* partB = smem + 512;
    __shared__ float cS;
    const int tid = threadIdx.x;
    const int n = blockIdx.x >> 4, og = blockIdx.x & 15;
    const int ol = tid & 15, ic = tid >> 4;   // 16 o-lanes x 32 i-chunks(4)
    const int o = og * 16 + ol;
    if (tid == 0) cS = ws[OFF_CNT + n];
    if (tid < MAXE) elS[tid] = ((const int*)(ws + OFF_EL))[n * MAXE + tid];
    if (tid >= 448) {
        const int q = tid - 448;
        *(float4*)&x1S[q * 4] = *(const float4*)(ws + OFF_X1 + n * 256 + q * 4);
    }
    __syncthreads();
    const int deg = (int)cS;
    const int dl = deg < MAXE ? deg : MAXE;
    if (tid < dl) {
        const int eid = elS[tid];
        srcS[tid] = ei[eid];
        const float2* eap = (const float2*)(ea + eid * 6);
        *(float2*)&easS[tid * 6] = eap[0];
        *(float2*)&easS[tid * 6 + 2] = eap[1];
        *(float2*)&easS[tid * 6 + 4] = eap[2];
    }
    float accm = 0.f;
    for (int p = 0; p < 2; ++p) {          // i-halves of 128
        __syncthreads();                   // srcS/easS ready; xs reusable
        for (int idx = tid; idx < dl * 32; idx += 512) {
            const int e = idx >> 5, ip = (idx & 31) * 4;
            *(float4*)&xsS[e * 128 + ip] =
                *(const float4*)(ws + OFF_X1 + srcS[e] * 256 + p * 128 + ip);
        }
        __syncthreads();
        const int i0 = p * 128 + ic * 4;
        const float* wp0 = w2 + (size_t)((i0 + 0) * 256 + o) * 6;
        const float* wp1 = w2 + (size_t)((i0 + 1) * 256 + o) * 6;
        const float* wp2 = w2 + (size_t)((i0 + 2) * 256 + o) * 6;
        const float* wp3 = w2 + (size_t)((i0 + 3) * 256 + o) * 6;
        const float2 wa0 = *(const float2*)wp0;
        const float2 wb0 = *(const float2*)(wp0 + 2);
        const float2 wc0 = *(const float2*)(wp0 + 4);
        const float2 wa1 = *(const float2*)wp1;
        const float2 wb1 = *(const float2*)(wp1 + 2);
        const float2 wc1 = *(const float2*)(wp1 + 4);
        const float2 wa2 = *(const float2*)wp2;
        const float2 wb2 = *(const float2*)(wp2 + 2);
        const float2 wc2 = *(const float2*)(wp2 + 4);
        const float2 wa3 = *(const float2*)wp3;
        const float2 wb3 = *(const float2*)(wp3 + 2);
        const float2 wc3 = *(const float2*)(wp3 + 4);
        const float bb0 = b2w[(i0 + 0) * 256 + o];
        const float bb1 = b2w[(i0 + 1) * 256 + o];
        const float bb2 = b2w[(i0 + 2) * 256 + o];
        const float bb3 = b2w[(i0 + 3) * 256 + o];
        for (int e = 0; e < dl; ++e) {
            const float2 e01 = *(const float2*)&easS[e * 6];
            const float2 e23 = *(const float2*)&easS[e * 6 + 2];
            const float2 e45 = *(const float2*)&easS[e * 6 + 4];
            const float4 xv = *(const float4*)&xsS[e * 128 + ic * 4];
            float d0 = bb0, d1 = bb1, d2 = bb2, d3 = bb3;
            d0 = fmaf(e01.x, wa0.x, d0); d1 = fmaf(e01.x, wa1.x, d1);
            d2 = fmaf(e01.x, wa2.x, d2); d3 = fmaf(e01.x, wa3.x, d3);
            d0 = fmaf(e01.y, wa0.y, d0); d1 = fmaf(e01.y, wa1.y, d1);
            d2 = fmaf(e01.y, wa2.y, d2); d3 = fmaf(e01.y, wa3.y, d3);
            d0 = fmaf(e23.x, wb0.x, d0); d1 = fmaf(e23.x, wb1.x, d1);
            d2 = fmaf(e23.x, wb2.x, d2); d3 = fmaf(e23.x, wb3.x, d3);
            d0 = fmaf(e23.y, wb0.y, d0); d1 = fmaf(e23.y, wb1.y, d1);
            d2 = fmaf(e23.y, wb2.y, d2); d3 = fmaf(e23.y, wb3.y, d3);
            d0 = fmaf(e45.x, wc0.x, d0); d1 = fmaf(e45.x, wc1.x, d1);
            d2 = fmaf(e45.x, wc2.x, d2); d3 = fmaf(e45.x, wc3.x, d3);
            d0 = fmaf(e45.y, wc0.y, d0); d1 = fmaf(e45.y, wc1.y, d1);
            d2 = fmaf(e45.y, wc2.y, d2); d3 = fmaf(e45.y, wc3.y, d3);
            d0 = fmaxf(d0, 0.f); d1 = fmaxf(d1, 0.f);
            d2 = fmaxf(d2, 0.f); d3 = fmaxf(d3, 0.f);
            accm = fmaf(xv.x, d0, accm);
            accm = fmaf(xv.y, d1, accm);
            accm = fmaf(xv.z, d2, accm);
            accm = fmaf(xv.w, d3, accm);
        }
    }
    // root (lin2) partial over this thread's 8 i's
    float accl = 0.f;
    {
        const float4 l0 = *(const float4*)(lin2 + (size_t)o * 256 + ic * 4);
        const float4 xa = *(const float4*)&x1S[ic * 4];
        accl = fmaf(l0.x, xa.x, accl); accl = fmaf(l0.y, xa.y, accl);
        accl = fmaf(l0.z, xa.z, accl); accl = fmaf(l0.w, xa.w, accl);
        const float4 l1 = *(const float4*)(lin2 + (size_t)o * 256 + 128 + ic * 4);
        const float4 xb = *(const float4*)&x1S[128 + ic * 4];
        accl = fmaf(l1.x, xb.x, accl); accl = fmaf(l1.y, xb.y, accl);
        accl = fmaf(l1.z, xb.z, accl); accl = fmaf(l1.w, xb.w, accl);
    }
    __syncthreads();                 // all xs reads done; partA aliases xsS
    partA[ic * 16 + ol] = accm;
    partB[ic * 16 + ol] = accl;
    __syncthreads();
    if (tid < 16) {
        float m = 0.f, l = 0.f;
        for (int k = 0; k < 32; ++k) {
            m += partA[k * 16 + tid];
            l += partB[k * 16 + tid];
        }
        const float c = fmaxf(cS, 1.f);
        ws[OFF_X2 + n * 256 + og * 16 + tid] =
            fmaxf(m / c + l + b2[og * 16 + tid], 0.f);
    }
}

// -------- K3: layer-3 partials + last-block x3 + last-node CBT -------------
__global__ __launch_bounds__(512) void p3c_k(
    float* __restrict__ ws, const float* __restrict__ ea,
    const int* __restrict__ ei, const float* __restrict__ w3,
    const float* __restrict__ b3w, const float* __restrict__ lin3,
    const float* __restrict__ b3, float* __restrict__ out) {
    __shared__ float xsS[MAXE * 32];       // 2560 (also reused: x2 row / sx)
    __shared__ float easS[MAXE * 6];       // 480
    __shared__ int srcS[MAXE];
    __shared__ int elS[MAXE];
    __shared__ float partS[8 * 64];
    __shared__ float cS;
    __shared__ int roleS;
    const int tid = threadIdx.x;
    const int n = blockIdx.x >> 3, iq = blockIdx.x & 7;
    const int i0 = iq * 32;
    const int ol = tid & 63, ic = tid >> 6;   // 64 o-lanes x 8 i-chunks(4)
    if (tid == 0) cS = ws[OFF_CNT + n];
    if (tid < MAXE) elS[tid] = ((const int*)(ws + OFF_EL))[n * MAXE + tid];
    __syncthreads();
    const int deg = (int)cS;
    const int dl = deg < MAXE ? deg : MAXE;
    if (tid < dl) {
        const int eid = elS[tid];
        srcS[tid] = ei[eid];
        const float2* eap = (const float2*)(ea + eid * 6);
        *(float2*)&easS[tid * 6] = eap[0];
        *(float2*)&easS[tid * 6 + 2] = eap[1];
        *(float2*)&easS[tid * 6 + 4] = eap[2];
    }
    __syncthreads();
    for (int idx = tid; idx < dl * 8; idx += 512) {
        const int e = idx >> 3, ip = (idx & 7) * 4;
        *(float4*)&xsS[e * 32 + ip] =
            *(const float4*)(ws + OFF_X2 + srcS[e] * 256 + i0 + ip);
    }
    __syncthreads();
    const int ib = i0 + ic * 4;
    const float* wp0 = w3 + (size_t)((ib + 0) * 64 + ol) * 6;
    const float* wp1 = w3 + (size_t)((ib + 1) * 64 + ol) * 6;
    const float* wp2 = w3 + (size_t)((ib + 2) * 64 + ol) * 6;
    const float* wp3 = w3 + (size_t)((ib + 3) * 64 + ol) * 6;
    const float2 wa0 = *(const float2*)wp0;
    const float2 wb0 = *(const float2*)(wp0 + 2);
    const float2 wc0 = *(const float2*)(wp0 + 4);
    const float2 wa1 = *(const float2*)wp1;
    const float2 wb1 = *(const float2*)(wp1 + 2);
    const float2 wc1 = *(const float2*)(wp1 + 4);
    const float2 wa2 = *(const float2*)wp2;
    const float2 wb2 = *(const float2*)(wp2 + 2);
    const float2 wc2 = *(const float2*)(wp2 + 4);
    const float2 wa3 = *(const float2*)wp3;
    const float2 wb3 = *(const float2*)(wp3 + 2);
    const float2 wc3 = *(const float2*)(wp3 + 4);
    const float bb0 = b3w[(ib + 0) * 64 + ol];
    const float bb1 = b3w[(ib + 1) * 64 + ol];
    const float bb2 = b3w[(ib + 2) * 64 + ol];
    const float bb3 = b3w[(ib + 3) * 64 + ol];
    float accm = 0.f;
    for (int e = 0; e < dl; ++e) {
        const float2 e01 = *(const float2*)&easS[e * 6];
        const float2 e23 = *(const float2*)&easS[e * 6 + 2];
        const float2 e45 = *(const float2*)&easS[e * 6 + 4];
        const float4 xv = *(const float4*)&xsS[e * 32 + ic * 4];
        float d0 = bb0, d1 = bb1, d2 = bb2, d3 = bb3;
        d0 = fmaf(e01.x, wa0.x, d0); d1 = fmaf(e01.x, wa1.x, d1);
        d2 = fmaf(e01.x, wa2.x, d2); d3 = fmaf(e01.x, wa3.x, d3);
        d0 = fmaf(e01.y, wa0.y, d0); d1 = fmaf(e01.y, wa1.y, d1);
        d2 = fmaf(e01.y, wa2.y, d2); d3 = fmaf(e01.y, wa3.y, d3);
        d0 = fmaf(e23.x, wb0.x, d0); d1 = fmaf(e23.x, wb1.x, d1);
        d2 = fmaf(e23.x, wb2.x, d2); d3 = fmaf(e23.x, wb3.x, d3);
        d0 = fmaf(e23.y, wb0.y, d0); d1 = fmaf(e23.y, wb1.y, d1);
        d2 = fmaf(e23.y, wb2.y, d2); d3 = fmaf(e23.y, wb3.y, d3);
        d0 = fmaf(e45.x, wc0.x, d0); d1 = fmaf(e45.x, wc1.x, d1);
        d2 = fmaf(e45.x, wc2.x, d2); d3 = fmaf(e45.x, wc3.x, d3);
        d0 = fmaf(e45.y, wc0.y, d0); d1 = fmaf(e45.y, wc1.y, d1);
        d2 = fmaf(e45.y, wc2.y, d2); d3 = fmaf(e45.y, wc3.y, d3);
        d0 = fmaxf(d0, 0.f); d1 = fmaxf(d1, 0.f);
        d2 = fmaxf(d2, 0.f); d3 = fmaxf(d3, 0.f);
        accm = fmaf(xv.x, d0, accm);
        accm = fmaf(xv.y, d1, accm);
        accm = fmaf(xv.z, d2, accm);
        accm = fmaf(xv.w, d3, accm);
    }
    partS[ic * 64 + ol] = accm;
    __syncthreads();
    if (ic == 0) {
        float s = accm;
#pragma unroll
        for (int p = 1; p < 8; ++p) s += partS[p * 64 + ol];
        atomicAdd(ws + OFF_AGG3 + n * 64 + ol, s);
    }
    // ---- closer election: vmcnt drained by __syncthreads, then count ----
    __syncthreads();
    if (tid == 0) {
        unsigned* cnt3 = (unsigned*)(ws + OFF_CNT3);
        const unsigned old = __hip_atomic_fetch_add(
            cnt3 + n, 1u, __ATOMIC_RELAXED, __HIP_MEMORY_SCOPE_AGENT);
        roleS = (old == 7u);
    }
    __syncthreads();
    if (!roleS) return;
    // ---- this block closes node n: x3[n] = relu(agg3/c + lin3.x2 + b3) ----
    {
        float* x2S = xsS;
        if (tid < 64)
            *(float4*)&x2S[tid * 4] =
                *(const float4*)(ws + OFF_X2 + n * 256 + tid * 4);
        __syncthreads();
        const int o3 = tid & 63, ic8 = tid >> 6;  // 8 chunks of 32 i
        const float4* l4 = (const float4*)(lin3 + (size_t)o3 * 256 + ic8 * 32);
        const float* xs = x2S + ic8 * 32;
        float s = 0.f;
#pragma unroll
        for (int k = 0; k < 8; k++) {
            const float4 wv = l4[k];
            s = fmaf(wv.x, xs[k * 4], s);
            s = fmaf(wv.y, xs[k * 4 + 1], s);
            s = fmaf(wv.z, xs[k * 4 + 2], s);
            s = fmaf(wv.w, xs[k * 4 + 3], s);
        }
        partS[ic8 * 64 + o3] = s;
        __syncthreads();
        if (ic8 == 0) {
            float t = s;
#pragma unroll
            for (int p = 1; p < 8; p++) t += partS[p * 64 + o3];
            const float g = ld_c(ws + OFF_AGG3 + n * 64 + o3);  // sc1: LLC truth
            const float c = fmaxf(cS, 1.f);
            st_c(ws + OFF_X3 + n * 64 + o3, fmaxf(g / c + t + b3[o3], 0.f));
        }
    }
    // ---- final election: last node-closer runs the CBT --------------------
    __syncthreads();  // drains wave0's x3 sc1 stores
    if (tid == 0) {
        unsigned* done = (unsigned*)(ws + OFF_DONE);
        const unsigned old = __hip_atomic_fetch_add(
            done, 1u, __ATOMIC_RELAXED, __HIP_MEMORY_SCOPE_AGENT);
        roleS = (old == NN - 1u);
    }
    __syncthreads();
    if (!roleS) return;
    {
        float* sx = xsS;  // 2240 <= 2560
        for (int idx = tid; idx < NN * 64; idx += 512)
            sx[idx] = ld_c(ws + OFF_X3 + idx);
        __syncthreads();
        const int f = tid & 63, jg = tid >> 6;
        for (int i = 0; i < NN; ++i) {
            const float xi = sx[i * 64 + f];
            for (int j = jg; j < NN; j += 8) {
                float d = fabsf(xi - sx[j * 64 + f]);
#pragma unroll
                for (int off = 32; off > 0; off >>= 1) d += __shfl_xor(d, off);
                if (f == 0) out[i * NN + j] = d;
            }
        }
    }
}

extern "C" void kernel_launch(void* const* d_in, const int* in_sizes, int n_in,
                              void* d_out, int out_size, void* d_ws, size_t ws_size,
                              hipStream_t stream) {
    (void)in_sizes; (void)n_in; (void)out_size; (void)ws_size;
    const float* x    = (const float*)d_in[0];
    const float* ea   = (const float*)d_in[1];
    const int*   ei   = (const int*)d_in[2];
    const float* nn1w = (const float*)d_in[3];
    const float* nn1b = (const float*)d_in[4];
    const float* lin1 = (const float*)d_in[5];
    const float* b1   = (const float*)d_in[6];
    const float* nn2w = (const float*)d_in[7];
    const float* nn2b = (const float*)d_in[8];
    const float* lin2 = (const float*)d_in[9];
    const float* b2   = (const float*)d_in[10];
    const float* nn3w = (const float*)d_in[11];
    const float* nn3b = (const float*)d_in[12];
    const float* lin3 = (const float*)d_in[13];
    const float* b3   = (const float*)d_in[14];

    float* ws = (float*)d_ws;
    x1_k<<<145, 512, 0, stream>>>(ws, x, ea, ei, nn1w, nn1b, lin1, b1);
    x2_k<<<NN * 16, 512, 0, stream>>>(ws, ea, ei, nn2w, nn2b, lin2, b2);
    p3c_k<<<NN * 8, 512, 0, stream>>>(ws, ea, ei, nn3w, nn3b, lin3, b3,
                                      (float*)d_out);
}